// Round 1
// baseline (1666.603 us; speedup 1.0000x reference)
//
#include <hip/hip_runtime.h>

// Problem constants
#define B_ 8
#define H_ 128
#define W_ 256
#define NPIX (B_*64*H_*W_)   // 16777216 elements of fused output
// Tile
#define TH 4
#define TW 64

// Direct 3x3 SAME conv + bias + ReLU.
// One output pixel per thread (256 threads = 4 waves = TH rows x TW cols),
// all Co output channels accumulated in registers.
// Input staged in LDS in CHUNK-channel slabs. Weights read with
// block-uniform indices -> scalar loads (s_load), leaving VALU for FMAs.
// If LOSS: instead of storing, compare against ref and atomicAdd the
// block-reduced sum of squared errors into *acc_out.
template<int Ci, int Co, int CHUNK, bool LOSS>
__global__ __launch_bounds__(256)
void conv3x3_kernel(const float* __restrict__ in, const float* __restrict__ wgt,
                    const float* __restrict__ bias, float* __restrict__ out,
                    const float* __restrict__ ref, float* __restrict__ acc_out)
{
    __shared__ float smem[CHUNK][TH + 2][TW + 2];

    const int tid = threadIdx.x;
    const int tx  = tid & 63;     // column within tile (one wave per row)
    const int ty  = tid >> 6;     // row within tile
    const int bx  = blockIdx.x;   // W_/TW tiles
    const int by  = blockIdx.y;   // H_/TH tiles
    const int bz  = blockIdx.z;   // batch

    const int h = by * TH + ty;
    const int w = bx * TW + tx;
    const int h0 = by * TH - 1;   // halo origin
    const int w0 = bx * TW - 1;

    float acc[Co];
#pragma unroll
    for (int co = 0; co < Co; ++co) acc[co] = 0.f;

    for (int c0 = 0; c0 < Ci; c0 += CHUNK) {
        if (c0) __syncthreads();
        // ---- stage CHUNK channels of (TH+2)x(TW+2) input (zero-padded halo)
        constexpr int E = CHUNK * (TH + 2) * (TW + 2);
        for (int i = tid; i < E; i += 256) {
            int c   = i / ((TH + 2) * (TW + 2));
            int rem = i - c * ((TH + 2) * (TW + 2));
            int r   = rem / (TW + 2);
            int col = rem - r * (TW + 2);
            int gh = h0 + r;
            int gw = w0 + col;
            float v = 0.f;
            if (gh >= 0 && gh < H_ && gw >= 0 && gw < W_)
                v = in[(((size_t)bz * Ci + (c0 + c)) * H_ + gh) * W_ + gw];
            smem[c][r][col] = v;
        }
        __syncthreads();

        // ---- accumulate
        for (int cc = 0; cc < CHUNK; ++cc) {
            float i00 = smem[cc][ty + 0][tx + 0];
            float i01 = smem[cc][ty + 0][tx + 1];
            float i02 = smem[cc][ty + 0][tx + 2];
            float i10 = smem[cc][ty + 1][tx + 0];
            float i11 = smem[cc][ty + 1][tx + 1];
            float i12 = smem[cc][ty + 1][tx + 2];
            float i20 = smem[cc][ty + 2][tx + 0];
            float i21 = smem[cc][ty + 2][tx + 1];
            float i22 = smem[cc][ty + 2][tx + 2];
            const float* wp = wgt + (size_t)(c0 + cc) * 9;
#pragma unroll
            for (int co = 0; co < Co; ++co) {
                const float* wk = wp + (size_t)co * Ci * 9;
                acc[co] += i00 * wk[0] + i01 * wk[1] + i02 * wk[2]
                         + i10 * wk[3] + i11 * wk[4] + i12 * wk[5]
                         + i20 * wk[6] + i21 * wk[7] + i22 * wk[8];
            }
        }
    }

    if (!LOSS) {
#pragma unroll
        for (int co = 0; co < Co; ++co) {
            float v = acc[co] + bias[co];
            v = v > 0.f ? v : 0.f;
            out[(((size_t)bz * Co + co) * H_ + h) * W_ + w] = v;
        }
    } else {
        float lsum = 0.f;
#pragma unroll
        for (int co = 0; co < Co; ++co) {
            float v = acc[co] + bias[co];
            v = v > 0.f ? v : 0.f;
            float d = ref[(((size_t)bz * Co + co) * H_ + h) * W_ + w] - v;
            lsum += d * d;
        }
        // wave(64)-level reduction, then one atomic per wave
#pragma unroll
        for (int off = 32; off > 0; off >>= 1)
            lsum += __shfl_down(lsum, off, 64);
        if ((tid & 63) == 0) atomicAdd(acc_out, lsum);
    }
}

// fused_feat = 0.5*(feat0+feat1), exactly (the m-softmax collapses to 1/2).
__global__ __launch_bounds__(256)
void fused_avg_kernel(const float4* __restrict__ a, const float4* __restrict__ b,
                      float4* __restrict__ o, int n4)
{
    int i = blockIdx.x * 256 + threadIdx.x;
    if (i < n4) {
        float4 x = a[i], y = b[i];
        float4 r;
        r.x = 0.5f * (x.x + y.x);
        r.y = 0.5f * (x.y + y.y);
        r.z = 0.5f * (x.z + y.z);
        r.w = 0.5f * (x.w + y.w);
        o[i] = r;
    }
}

__global__ void finalize_loss_kernel(float* acc)
{
    *acc *= (1.0f / (float)NPIX);   // sum0+sum1 over a common divisor B*C*H*W
}

extern "C" void kernel_launch(void* const* d_in, const int* in_sizes, int n_in,
                              void* d_out, int out_size, void* d_ws, size_t ws_size,
                              hipStream_t stream)
{
    const float* feat0 = (const float*)d_in[0];
    const float* feat1 = (const float*)d_in[1];
    const float* w1 = (const float*)d_in[2];
    const float* b1 = (const float*)d_in[3];
    const float* w2 = (const float*)d_in[4];
    const float* b2 = (const float*)d_in[5];
    const float* w3 = (const float*)d_in[6];
    const float* b3 = (const float*)d_in[7];
    const float* w4 = (const float*)d_in[8];
    const float* b4 = (const float*)d_in[9];
    // d_in[10] = modality_adapter (unused by the reference forward)

    float* out  = (float*)d_out;
    // Scratch lives inside d_out (it is overwritten by the final kernels):
    float* buf1 = out;              // [B,32,H,W] = 8388608 floats (32 MB)
    float* buf2 = out + 8388608;    // [B,16,H,W] = 4194304 floats (16 MB)
    float* acc  = out + NPIX;       // loss accumulator / final loss slot

    hipMemsetAsync(acc, 0, sizeof(float), stream);

    dim3 grid(W_ / TW, H_ / TH, B_);
    dim3 blk(256);

    const float* feats[2] = { feat0, feat1 };
    for (int m = 0; m < 2; ++m) {
        // 64 -> 32
        conv3x3_kernel<64, 32, 16, false><<<grid, blk, 0, stream>>>(
            feats[m], w1, b1, buf1, nullptr, nullptr);
        // 32 -> 16 (bottleneck; SVD path is dead code — never affects outputs)
        conv3x3_kernel<32, 16, 16, false><<<grid, blk, 0, stream>>>(
            buf1, w2, b2, buf2, nullptr, nullptr);
        // 16 -> 32
        conv3x3_kernel<16, 32, 16, false><<<grid, blk, 0, stream>>>(
            buf2, w3, b3, buf1, nullptr, nullptr);
        // 32 -> 64 fused with sum((f - rec)^2) reduction (rec never stored)
        conv3x3_kernel<32, 64, 16, true><<<grid, blk, 0, stream>>>(
            buf1, w4, b4, nullptr, feats[m], acc);
    }

    // fused_feat = 0.5*(feat0+feat1); overwrites the scratch region last.
    int n4 = NPIX / 4;
    fused_avg_kernel<<<(n4 + 255) / 256, 256, 0, stream>>>(
        (const float4*)feat0, (const float4*)feat1, (float4*)out, n4);

    finalize_loss_kernel<<<1, 1, 0, stream>>>(acc);
}

// Round 2
// 538.939 us; speedup vs baseline: 3.0924x; 3.0924x over previous
//
#include <hip/hip_runtime.h>
#include <hip/hip_bf16.h>

#define B_ 8
#define H_ 128
#define W_ 256
#define PH 130          // H + 2 zero-pad rows
#define PW 258          // W + 2 zero-pad cols
#define NPIX (B_*64*H_*W_)   // 16777216 fused-output elements

typedef short short8 __attribute__((ext_vector_type(8)));   // 8 bf16 (4 VGPRs)
typedef float floatx4 __attribute__((ext_vector_type(4)));  // MFMA C/D

// ---------------------------------------------------------------------------
// Implicit-GEMM 3x3 SAME conv + bias + ReLU on bf16 MFMA 16x16x32.
// Input:  zero-padded NHWC bf16 [B][PH][PW][Ci]  (pad = SAME zeros)
// Weight: pre-transformed [KC][Co][32] bf16 (kchunk-major, see wt_transform)
// Block = 256 threads = 4 waves; one full image row; wave w covers 64 pixels
// as 4 m-tiles of 16. GEMM: D[m=pixel][n=co] = sum_k A[m][k]*B[k][n].
// A-frag: lane m=lane&15, k=quad*8+j -> 16B contiguous channels of one pixel.
// B-frag: lane n=lane&15, k=quad*8+j -> 16B contiguous in wt layout.
// C/D   : col(n)=lane&15, row(m)=quad*4+reg.   No LDS, no barriers.
// LOSS: instead of storing, accumulate sum((ref - relu(acc+bias))^2).
// ---------------------------------------------------------------------------
template<int Ci, int Co, bool LOSS>
__global__ __launch_bounds__(256)
void conv_mfma(const __hip_bfloat16* __restrict__ in,
               const __hip_bfloat16* __restrict__ wt,
               const float* __restrict__ bias,
               __hip_bfloat16* __restrict__ outp,
               const float* __restrict__ ref,   // fp32 NCHW (LOSS only)
               float* __restrict__ acc_out)
{
    constexpr int KC = (Ci >= 32) ? 9*(Ci/32) : 6;   // K-chunks of 32
    constexpr int NT = Co/16;                        // n-tiles

    const int tid  = threadIdx.x;
    const int lane = tid & 63;
    const int wid  = tid >> 6;
    const int col  = lane & 15;
    const int quad = lane >> 4;
    const int h    = blockIdx.x;
    const int bz   = blockIdx.y;

    floatx4 acc[4][NT];
#pragma unroll
    for (int mt = 0; mt < 4; ++mt)
#pragma unroll
        for (int nt = 0; nt < NT; ++nt)
            acc[mt][nt] = (floatx4)0.f;

    const __hip_bfloat16* inb = in + (size_t)bz * PH * PW * Ci;

#pragma unroll
    for (int kc = 0; kc < KC; ++kc) {
        int dy, dxb, cib;
        if (Ci >= 32) {
            constexpr int CC = Ci/32;
            int t = kc / CC, c2 = kc % CC;      // tap, ci-chunk (constexpr folds)
            dy  = t / 3;
            dxb = t % 3;                        // padded col offset = w + dx
            cib = c2*32 + quad*8;
        } else {
            // Ci=16: chunk = (dy, half); half0 packs dx{0,1}, half1 packs dx{2, zero-pad}
            dy  = kc >> 1;
            int half = kc & 1;
            dxb = half*2 + (quad >> 1);         // quad>=2 of half1 hits zero weights
            cib = (quad & 1) * 8;
        }
        const __hip_bfloat16* rowp = inb + (size_t)(h + dy) * PW * Ci;

        short8 a[4];
#pragma unroll
        for (int mt = 0; mt < 4; ++mt) {
            int wcol = wid*64 + mt*16 + col + dxb;   // padded col index
            a[mt] = *(const short8*)(rowp + (size_t)wcol * Ci + cib);
        }
#pragma unroll
        for (int nt = 0; nt < NT; ++nt) {
            short8 b = *(const short8*)(wt + ((size_t)kc*Co + nt*16 + col)*32 + quad*8);
#pragma unroll
            for (int mt = 0; mt < 4; ++mt)
                acc[mt][nt] = __builtin_amdgcn_mfma_f32_16x16x32_bf16(
                                  a[mt], b, acc[mt][nt], 0, 0, 0);
        }
    }

    if (!LOSS) {
#pragma unroll
        for (int nt = 0; nt < NT; ++nt) {
            int co = nt*16 + col;
            float bv = bias[co];
#pragma unroll
            for (int mt = 0; mt < 4; ++mt) {
#pragma unroll
                for (int r = 0; r < 4; ++r) {
                    int w = wid*64 + mt*16 + quad*4 + r;    // D row = pixel
                    float v = acc[mt][nt][r] + bv;
                    v = v > 0.f ? v : 0.f;
                    outp[(((size_t)bz*PH + (h+1))*PW + (w+1))*Co + co] =
                        __float2bfloat16(v);
                }
            }
        }
    } else {
        float lsum = 0.f;
#pragma unroll
        for (int nt = 0; nt < NT; ++nt) {
            int co = nt*16 + col;
            float bv = bias[co];
            const float* refc = ref + (((size_t)bz*Co + co)*H_ + h)*W_;
#pragma unroll
            for (int mt = 0; mt < 4; ++mt) {
                int wb = wid*64 + mt*16 + quad*4;
                float4 f = *(const float4*)(refc + wb);
                float d0 = f.x - fmaxf(acc[mt][nt][0] + bv, 0.f);
                float d1 = f.y - fmaxf(acc[mt][nt][1] + bv, 0.f);
                float d2 = f.z - fmaxf(acc[mt][nt][2] + bv, 0.f);
                float d3 = f.w - fmaxf(acc[mt][nt][3] + bv, 0.f);
                lsum += d0*d0 + d1*d1 + d2*d2 + d3*d3;
            }
        }
#pragma unroll
        for (int off = 32; off > 0; off >>= 1)
            lsum += __shfl_down(lsum, off, 64);
        if (lane == 0) atomicAdd(acc_out, lsum);
    }
}

// ---------------------------------------------------------------------------
// fp32 NCHW feat -> bf16 zero-padded NHWC (interior only; pads pre-zeroed).
// LDS transpose so both global read (along w) and write (along c) coalesce.
// ---------------------------------------------------------------------------
__global__ __launch_bounds__(256)
void feat_to_nhwc(const float* __restrict__ src, __hip_bfloat16* __restrict__ dst)
{
    __shared__ float tile[64][65];
    const int tid = threadIdx.x;
    const int w0 = blockIdx.x * 64;
    const int h  = blockIdx.y;
    const int bz = blockIdx.z;

#pragma unroll
    for (int i = 0; i < 16; ++i) {
        int c = i*4 + (tid >> 6);
        int w = tid & 63;
        tile[c][w] = src[(((size_t)bz*64 + c)*H_ + h)*W_ + w0 + w];
    }
    __syncthreads();
#pragma unroll
    for (int i = 0; i < 16; ++i) {
        int w = i*4 + (tid >> 6);
        int c = tid & 63;
        dst[(((size_t)bz*PH + (h+1))*PW + (w0 + w + 1))*64 + c] =
            __float2bfloat16(tile[c][w]);
    }
}

// ---------------------------------------------------------------------------
// OIHW fp32 weights -> [KC][Co][32] bf16 B-operand layout (with zero pads
// for the Ci=16 half-chunks).
// ---------------------------------------------------------------------------
template<int Ci, int Co>
__global__ void wt_transform(const float* __restrict__ w, __hip_bfloat16* __restrict__ wt)
{
    constexpr int KC = (Ci >= 32) ? 9*(Ci/32) : 6;
    int idx = blockIdx.x*256 + threadIdx.x;
    if (idx >= KC*Co*32) return;
    int kl = idx & 31;
    int co = (idx >> 5) % Co;
    int kc = idx / (32*Co);
    float val = 0.f;
    if (Ci >= 32) {
        constexpr int CC = Ci/32;
        int t = kc / CC, c2 = kc % CC;
        int dy = t/3, dx = t%3;
        int ci = c2*32 + kl;
        val = w[((size_t)(co*Ci + ci)*3 + dy)*3 + dx];
    } else {
        int dy = kc >> 1, half = kc & 1;
        int dx = half*2 + (kl >> 4);
        int ci = kl & 15;
        if (dx < 3) val = w[((size_t)(co*Ci + ci)*3 + dy)*3 + dx];
        // dx==3 -> zero pad
    }
    wt[idx] = __float2bfloat16(val);
}

// fused_feat = 0.5*(feat0+feat1) exactly (the m-softmax collapses to 1/2).
__global__ __launch_bounds__(256)
void fused_avg_kernel(const float4* __restrict__ a, const float4* __restrict__ b,
                      float4* __restrict__ o, int n4)
{
    int i = blockIdx.x*256 + threadIdx.x;
    if (i < n4) {
        float4 x = a[i], y = b[i];
        float4 r;
        r.x = 0.5f*(x.x + y.x);
        r.y = 0.5f*(x.y + y.y);
        r.z = 0.5f*(x.z + y.z);
        r.w = 0.5f*(x.w + y.w);
        o[i] = r;
    }
}

__global__ void finalize_loss_kernel(float* acc)
{
    *acc *= (1.0f / (float)NPIX);
}

extern "C" void kernel_launch(void* const* d_in, const int* in_sizes, int n_in,
                              void* d_out, int out_size, void* d_ws, size_t ws_size,
                              hipStream_t stream)
{
    const float* feat0 = (const float*)d_in[0];
    const float* feat1 = (const float*)d_in[1];
    const float* w1 = (const float*)d_in[2];
    const float* b1 = (const float*)d_in[3];
    const float* w2 = (const float*)d_in[4];
    const float* b2 = (const float*)d_in[5];
    const float* w3 = (const float*)d_in[6];
    const float* b3 = (const float*)d_in[7];
    const float* w4 = (const float*)d_in[8];
    const float* b4 = (const float*)d_in[9];

    float* out = (float*)d_out;
    char*  base = (char*)d_out;

    // Scratch layout inside d_out (overwritten by fused_avg at the very end).
    // Padded NHWC pixel count per buffer: 8*130*258 = 268320.
    __hip_bfloat16* TF   = (__hip_bfloat16*)(base + 0);           // 64ch: 34,344,960 B
    __hip_bfloat16* BUF1 = (__hip_bfloat16*)(base + 34344960);    // 32ch: 17,172,480 B
    __hip_bfloat16* BUF2 = (__hip_bfloat16*)(base + 51517440);    // 16ch:  8,586,240 B
    __hip_bfloat16* WT1  = (__hip_bfloat16*)(base + 60103680);    // 18*32*32 bf16
    __hip_bfloat16* WT2  = (__hip_bfloat16*)(base + 60140544);    //  9*16*32
    __hip_bfloat16* WT3  = (__hip_bfloat16*)(base + 60149760);    //  6*32*32
    __hip_bfloat16* WT4  = (__hip_bfloat16*)(base + 60162048);    //  9*64*32  (end 60,198,912 < 64MB)
    float* acc = out + NPIX;                                      // loss slot

    // Zero the padded activation buffers (pad rows/cols must be 0 every call;
    // harness re-poisons d_out with 0xAA) and the loss accumulator.
    hipMemsetAsync(base, 0, 60103680, stream);
    hipMemsetAsync(acc, 0, sizeof(float), stream);

    // Weight transforms (tiny).
    wt_transform<64,32><<<(18*32*32 + 255)/256, 256, 0, stream>>>(w1, WT1);
    wt_transform<32,16><<<( 9*16*32 + 255)/256, 256, 0, stream>>>(w2, WT2);
    wt_transform<16,32><<<( 6*32*32 + 255)/256, 256, 0, stream>>>(w3, WT3);
    wt_transform<32,64><<<( 9*64*32 + 255)/256, 256, 0, stream>>>(w4, WT4);

    dim3 cgrid(H_, B_);   // one block per image row
    dim3 blk(256);
    dim3 tgrid(W_/64, H_, B_);

    const float* feats[2] = { feat0, feat1 };
    for (int m = 0; m < 2; ++m) {
        feat_to_nhwc<<<tgrid, blk, 0, stream>>>(feats[m], TF);
        conv_mfma<64,32,false><<<cgrid, blk, 0, stream>>>(TF,   WT1, b1, BUF1, nullptr, nullptr);
        conv_mfma<32,16,false><<<cgrid, blk, 0, stream>>>(BUF1, WT2, b2, BUF2, nullptr, nullptr);
        conv_mfma<16,32,false><<<cgrid, blk, 0, stream>>>(BUF2, WT3, b3, BUF1, nullptr, nullptr);
        conv_mfma<32,64,true ><<<cgrid, blk, 0, stream>>>(BUF1, WT4, b4, nullptr, feats[m], acc);
    }

    int n4 = NPIX/4;
    fused_avg_kernel<<<(n4 + 255)/256, 256, 0, stream>>>(
        (const float4*)feat0, (const float4*)feat1, (float4*)out, n4);

    finalize_loss_kernel<<<1, 1, 0, stream>>>(acc);
}

// Round 3
// 484.518 us; speedup vs baseline: 3.4397x; 1.1123x over previous
//
#include <hip/hip_runtime.h>
#include <hip/hip_bf16.h>

#define B_ 8
#define H_ 128
#define W_ 256
#define PH 130          // H + 2 zero-pad rows
#define PW 258          // W + 2 zero-pad cols
#define NPIX (B_*64*H_*W_)

typedef short short8 __attribute__((ext_vector_type(8)));   // 8 bf16 (4 VGPRs)
typedef float floatx4 __attribute__((ext_vector_type(4)));  // MFMA C/D

// ---------------------------------------------------------------------------
// Implicit-GEMM 3x3 SAME conv + bias + ReLU, bf16 MFMA 16x16x32, LDS-staged.
// Block = 256 thr = 4 waves; computes 4 output rows x 64 px x all Co.
// Wave w owns output row (h0+w): 4 m-tiles of 16 px, NT n-tiles of 16 co.
// LDS slab: [6 rows][66 px][Ci ch] bf16, 16B-chunk XOR swizzle
// (chunk ^= px & (NCB-1)) so both the contiguous staging writes and the
// px-strided A-fragment reads are bank-uniform (8 acc/bank = b128 minimum).
// Staging: fully coalesced global dwordx4 -> ds_write_b128; 1 barrier pair.
// Epilogue (non-LOSS): LDS transpose (per-wave region, padded Co+8 stride)
// -> 1KB-contiguous global stores. LOSS: fused sum((ref-relu)^2) -> atomic.
// Fragment conventions identical to round-2 (validated, absmax 0.0).
// ---------------------------------------------------------------------------
template<int Ci, int Co, bool LOSS>
__global__ __launch_bounds__(256)
void conv_mfma(const __hip_bfloat16* __restrict__ in,   // padded NHWC [B][PH][PW][Ci]
               const __hip_bfloat16* __restrict__ wt,   // [KC][Co][32] bf16
               const float* __restrict__ bias,
               __hip_bfloat16* __restrict__ outp,       // padded NHWC [B][PH][PW][Co]
               const float* __restrict__ ref,           // fp32 NCHW (LOSS only)
               float* __restrict__ acc_out)
{
    constexpr int CC   = (Ci >= 32) ? Ci/32 : 1;   // K chunks of 32 per tap
    constexpr int PXB  = Ci*2;                     // bytes per pixel in slab
    constexpr int NCB  = PXB/16;                   // 16B chunks per pixel
    constexpr int SLAB = 6*66*PXB;
    constexpr int NT   = Co/16;
    constexpr int EPIW = 64*(Co+8)*2;              // per-wave epilogue tile
    constexpr int LDSZ = (!LOSS && 4*EPIW > SLAB) ? 4*EPIW : SLAB;
    __shared__ alignas(16) char slab[LDSZ + 32];

    const int tid  = threadIdx.x;
    const int lane = tid & 63;
    const int wid  = tid >> 6;
    const int col  = lane & 15;
    const int quad = lane >> 4;
    const int w0   = blockIdx.x * 64;
    const int h0   = blockIdx.y * 4;
    const int bz   = blockIdx.z;
    const int r    = wid;                          // wave's output row in tile

    floatx4 acc[4][NT];
#pragma unroll
    for (int mt = 0; mt < 4; ++mt)
#pragma unroll
        for (int nt = 0; nt < NT; ++nt)
            acc[mt][nt] = (floatx4)0.f;

    const __hip_bfloat16* inb = in + (size_t)bz * PH * PW * Ci;

    // ---- stage slab: padded rows h0..h0+5, padded cols w0..w0+65, all Ci.
    // Global side fully coalesced (consecutive threads -> consecutive 16B).
    for (int o = tid*16; o < SLAB; o += 4096) {
        int pxl = o / PXB;                // pow2 shift
        int row = pxl / 66;
        int pxc = pxl - row*66;
        int cb  = (o >> 4) & (NCB-1);
        short8 v = *(const short8*)(inb + ((size_t)(h0+row)*PW + (w0+pxc))*Ci + cb*8);
        *(short8*)(slab + pxl*PXB + ((cb ^ (pxl & (NCB-1))) << 4)) = v;
    }
    __syncthreads();

    if constexpr (Ci >= 32) {
#pragma unroll
        for (int c2 = 0; c2 < CC; ++c2) {
#pragma unroll
            for (int t = 0; t < 9; ++t) {
                const int dy = t/3, dx = t - (t/3)*3;
                short8 a[4];
#pragma unroll
                for (int mt = 0; mt < 4; ++mt) {
                    int px = (r+dy)*66 + mt*16 + col + dx;
                    a[mt] = *(const short8*)(slab + px*PXB
                              + (((c2*4 + quad) ^ (px & (NCB-1))) << 4));
                }
#pragma unroll
                for (int nt = 0; nt < NT; ++nt) {
                    short8 b = *(const short8*)(wt
                        + ((size_t)(c2*9 + t)*Co + nt*16 + col)*32 + quad*8);
#pragma unroll
                    for (int mt = 0; mt < 4; ++mt)
                        acc[mt][nt] = __builtin_amdgcn_mfma_f32_16x16x32_bf16(
                                          a[mt], b, acc[mt][nt], 0, 0, 0);
                }
            }
        }
    } else {
        // Ci=16: K=32 packs 2 dx taps; half1's upper quads carry zero weights
        // and re-read dx=2 (valid data * 0 = 0, avoids NaN from junk LDS).
#pragma unroll
        for (int kc = 0; kc < 6; ++kc) {
            const int dy = kc >> 1, half = kc & 1;
            const int dxe = half ? 2 : (quad >> 1);
            short8 a[4];
#pragma unroll
            for (int mt = 0; mt < 4; ++mt) {
                int px = (r+dy)*66 + mt*16 + col + dxe;
                a[mt] = *(const short8*)(slab + px*PXB
                          + (((quad & 1) ^ (px & 1)) << 4));
            }
#pragma unroll
            for (int nt = 0; nt < NT; ++nt) {
                short8 b = *(const short8*)(wt
                    + ((size_t)kc*Co + nt*16 + col)*32 + quad*8);
#pragma unroll
                for (int mt = 0; mt < 4; ++mt)
                    acc[mt][nt] = __builtin_amdgcn_mfma_f32_16x16x32_bf16(
                                      a[mt], b, acc[mt][nt], 0, 0, 0);
            }
        }
    }

    if constexpr (!LOSS) {
        __syncthreads();          // slab raw data no longer needed by any wave
        char* rt = slab + wid * EPIW;     // per-wave [64 px][Co+8] bf16 tile
#pragma unroll
        for (int nt = 0; nt < NT; ++nt) {
            float bv = bias[nt*16 + col];
#pragma unroll
            for (int mt = 0; mt < 4; ++mt) {
#pragma unroll
                for (int rr = 0; rr < 4; ++rr) {
                    float v = acc[mt][nt][rr] + bv;
                    v = v > 0.f ? v : 0.f;
                    int px = mt*16 + quad*4 + rr;
                    *(__hip_bfloat16*)(rt + (px*(Co+8) + nt*16 + col)*2) =
                        __float2bfloat16(v);
                }
            }
        }
        // contiguous 1KB global stores of this wave's output row segment
        char* grow = (char*)outp
            + (((size_t)bz*PH + (h0 + r + 1))*PW + (w0 + 1))*Co*2;
        constexpr int GB = 64*Co*2;
#pragma unroll
        for (int id = 0; id < GB/1024; ++id) {
            int o  = id*1024 + lane*16;
            int px = o / (Co*2);
            int cb = o - px*(Co*2);
            *(short8*)(grow + o) = *(const short8*)(rt + px*(Co+8)*2 + cb);
        }
    } else {
        float lsum = 0.f;
#pragma unroll
        for (int nt = 0; nt < NT; ++nt) {
            float bv = bias[nt*16 + col];
            const float* refc = ref
                + (((size_t)bz*Co + nt*16 + col)*H_ + (h0 + r))*W_ + w0;
#pragma unroll
            for (int mt = 0; mt < 4; ++mt) {
                float4 f = *(const float4*)(refc + mt*16 + quad*4);
                float d0 = f.x - fmaxf(acc[mt][nt][0] + bv, 0.f);
                float d1 = f.y - fmaxf(acc[mt][nt][1] + bv, 0.f);
                float d2 = f.z - fmaxf(acc[mt][nt][2] + bv, 0.f);
                float d3 = f.w - fmaxf(acc[mt][nt][3] + bv, 0.f);
                lsum += d0*d0 + d1*d1 + d2*d2 + d3*d3;
            }
        }
#pragma unroll
        for (int off = 32; off > 0; off >>= 1)
            lsum += __shfl_down(lsum, off, 64);
        if (lane == 0) atomicAdd(acc_out, lsum);
    }
}

// ---------------------------------------------------------------------------
// fp32 NCHW feat -> bf16 padded-NHWC interior (pads zeroed separately).
// ---------------------------------------------------------------------------
__global__ __launch_bounds__(256)
void feat_to_nhwc(const float* __restrict__ src, __hip_bfloat16* __restrict__ dst)
{
    __shared__ float tile[64][65];
    const int tid = threadIdx.x;
    const int w0 = blockIdx.x * 64;
    const int h  = blockIdx.y;
    const int bz = blockIdx.z;

#pragma unroll
    for (int i = 0; i < 16; ++i) {
        int c = i*4 + (tid >> 6);
        int w = tid & 63;
        tile[c][w] = src[(((size_t)bz*64 + c)*H_ + h)*W_ + w0 + w];
    }
    __syncthreads();
#pragma unroll
    for (int i = 0; i < 16; ++i) {
        int w = i*4 + (tid >> 6);
        int c = tid & 63;
        dst[(((size_t)bz*PH + (h+1))*PW + (w0 + w + 1))*64 + c] =
            __float2bfloat16(tile[c][w]);
    }
}

// ---------------------------------------------------------------------------
// Zero only the pad border cells of a padded NHWC buffer (772 px / image).
// ---------------------------------------------------------------------------
template<int C>
__global__ void zero_border(__hip_bfloat16* buf)
{
    constexpr int CP = C/8;                  // 16B chunks per pixel
    int idx = blockIdx.x*256 + threadIdx.x;
    int total = B_ * 772 * CP;
    if (idx >= total) return;
    int cb   = idx % CP;
    int cell = (idx / CP) % 772;
    int img  = idx / (CP*772);
    int row, colp;
    if (cell < 258)      { row = 0;   colp = cell; }
    else if (cell < 516) { row = 129; colp = cell - 258; }
    else { int r2 = cell - 516; row = 1 + (r2 >> 1); colp = (r2 & 1) ? 257 : 0; }
    short8 z = (short8)0;
    *(short8*)(buf + (((size_t)img*PH + row)*PW + colp)*C + cb*8) = z;
}

// ---------------------------------------------------------------------------
// OIHW fp32 -> [KC][Co][32] bf16 B-operand layout. Ci>=32: kc = c2*9 + tap
// (chunk-major, matches kernel loop). Ci=16: kc = dy*2+half, dx slot 3 = 0.
// ---------------------------------------------------------------------------
template<int Ci, int Co>
__global__ void wt_transform(const float* __restrict__ w, __hip_bfloat16* __restrict__ wt)
{
    constexpr int KC = (Ci >= 32) ? 9*(Ci/32) : 6;
    int idx = blockIdx.x*256 + threadIdx.x;
    if (idx >= KC*Co*32) return;
    int kl = idx & 31;
    int co = (idx >> 5) % Co;
    int kc = idx / (32*Co);
    float val = 0.f;
    if (Ci >= 32) {
        int c2 = kc / 9, t = kc % 9;
        int dy = t/3, dx = t%3;
        int ci = c2*32 + kl;
        val = w[((size_t)(co*Ci + ci)*3 + dy)*3 + dx];
    } else {
        int dy = kc >> 1, half = kc & 1;
        int dx = half*2 + (kl >> 4);
        int ci = kl & 15;
        if (dx < 3) val = w[((size_t)(co*Ci + ci)*3 + dy)*3 + dx];
    }
    wt[idx] = __float2bfloat16(val);
}

// fused_feat = 0.5*(feat0+feat1) exactly (the m-softmax collapses to 1/2).
__global__ __launch_bounds__(256)
void fused_avg_kernel(const float4* __restrict__ a, const float4* __restrict__ b,
                      float4* __restrict__ o, int n4)
{
    int i = blockIdx.x*256 + threadIdx.x;
    if (i < n4) {
        float4 x = a[i], y = b[i];
        float4 r;
        r.x = 0.5f*(x.x + y.x);
        r.y = 0.5f*(x.y + y.y);
        r.z = 0.5f*(x.z + y.z);
        r.w = 0.5f*(x.w + y.w);
        o[i] = r;
    }
}

__global__ void finalize_loss_kernel(float* acc)
{
    *acc *= (1.0f / (float)NPIX);
}

extern "C" void kernel_launch(void* const* d_in, const int* in_sizes, int n_in,
                              void* d_out, int out_size, void* d_ws, size_t ws_size,
                              hipStream_t stream)
{
    const float* feat0 = (const float*)d_in[0];
    const float* feat1 = (const float*)d_in[1];
    const float* w1 = (const float*)d_in[2];
    const float* b1 = (const float*)d_in[3];
    const float* w2 = (const float*)d_in[4];
    const float* b2 = (const float*)d_in[5];
    const float* w3 = (const float*)d_in[6];
    const float* b3 = (const float*)d_in[7];
    const float* w4 = (const float*)d_in[8];
    const float* b4 = (const float*)d_in[9];

    float* out = (float*)d_out;
    char*  base = (char*)d_out;

    // Scratch inside d_out (overwritten by fused_avg at the end).
    __hip_bfloat16* TF   = (__hip_bfloat16*)(base + 0);           // 64ch padded NHWC
    __hip_bfloat16* BUF1 = (__hip_bfloat16*)(base + 34344960);    // 32ch
    __hip_bfloat16* BUF2 = (__hip_bfloat16*)(base + 51517440);    // 16ch
    __hip_bfloat16* WT1  = (__hip_bfloat16*)(base + 60103680);    // 18*32*32
    __hip_bfloat16* WT2  = (__hip_bfloat16*)(base + 60140544);    //  9*16*32
    __hip_bfloat16* WT3  = (__hip_bfloat16*)(base + 60149760);    //  6*32*32
    __hip_bfloat16* WT4  = (__hip_bfloat16*)(base + 60162048);    //  9*64*32
    float* acc = out + NPIX;                                      // loss slot

    hipMemsetAsync(acc, 0, sizeof(float), stream);

    // Zero only pad borders (interiors are fully rewritten every call).
    zero_border<64><<<(B_*772*8  + 255)/256, 256, 0, stream>>>(TF);
    zero_border<32><<<(B_*772*4  + 255)/256, 256, 0, stream>>>(BUF1);
    zero_border<16><<<(B_*772*2  + 255)/256, 256, 0, stream>>>(BUF2);

    wt_transform<64,32><<<(18*32*32 + 255)/256, 256, 0, stream>>>(w1, WT1);
    wt_transform<32,16><<<( 9*16*32 + 255)/256, 256, 0, stream>>>(w2, WT2);
    wt_transform<16,32><<<( 6*32*32 + 255)/256, 256, 0, stream>>>(w3, WT3);
    wt_transform<32,64><<<( 9*64*32 + 255)/256, 256, 0, stream>>>(w4, WT4);

    dim3 cgrid(W_/64, H_/4, B_);      // 4 x 32 x 8 = 1024 blocks
    dim3 blk(256);
    dim3 tgrid(W_/64, H_, B_);

    const float* feats[2] = { feat0, feat1 };
    for (int m = 0; m < 2; ++m) {
        feat_to_nhwc<<<tgrid, blk, 0, stream>>>(feats[m], TF);
        conv_mfma<64,32,false><<<cgrid, blk, 0, stream>>>(TF,   WT1, b1, BUF1, nullptr, nullptr);
        conv_mfma<32,16,false><<<cgrid, blk, 0, stream>>>(BUF1, WT2, b2, BUF2, nullptr, nullptr);
        conv_mfma<16,32,false><<<cgrid, blk, 0, stream>>>(BUF2, WT3, b3, BUF1, nullptr, nullptr);
        conv_mfma<32,64,true ><<<cgrid, blk, 0, stream>>>(BUF1, WT4, b4, nullptr, feats[m], acc);
    }

    int n4 = NPIX/4;
    fused_avg_kernel<<<(n4 + 255)/256, 256, 0, stream>>>(
        (const float4*)feat0, (const float4*)feat1, (float4*)out, n4);

    finalize_loss_kernel<<<1, 1, 0, stream>>>(acc);
}

// Round 4
// 379.673 us; speedup vs baseline: 4.3896x; 1.2761x over previous
//
#include <hip/hip_runtime.h>
#include <hip/hip_bf16.h>

#define B_ 8
#define H_ 128
#define W_ 256
#define PH 130          // H + 2 zero-pad rows
#define PW 258          // W + 2 zero-pad cols
#define NPIX (B_*64*H_*W_)

typedef short short8  __attribute__((ext_vector_type(8)));  // 8 bf16 (4 VGPRs)
typedef short short4v __attribute__((ext_vector_type(4)));  // 4 bf16 (8 B)
typedef float floatx4 __attribute__((ext_vector_type(4)));  // MFMA C/D

// ---------------------------------------------------------------------------
// Implicit-GEMM 3x3 SAME conv + bias + ReLU, bf16 MFMA 16x16x32, LDS-staged.
// Block = 256 thr = 4 waves; 4 output rows x 64 px x all Co. Wave r owns row.
// K-loop restructured (R4): B-fragments preloaded in BATCHES of 9*GNT
// independent global loads (forces deep VGPR liveness -> overlapped latency),
// then 9 taps of swizzled ds_read_b128 A-fragments + MFMA.
// LOSS epilogue (R4): rec -> LDS bf16 [co][row][68px] (aligned b64 writes),
// then block-cooperative COALESCED fp32 ref reads (256B contiguous per co),
// squared-diff reduce, ONE atomic per block.
// ---------------------------------------------------------------------------
template<int Ci, int Co, bool LOSS>
__global__ __launch_bounds__(256)
void conv_mfma(const __hip_bfloat16* __restrict__ in,   // padded NHWC [B][PH][PW][Ci]
               const __hip_bfloat16* __restrict__ wt,   // [KC][Co][32] bf16
               const float* __restrict__ bias,
               __hip_bfloat16* __restrict__ outp,       // padded NHWC [B][PH][PW][Co]
               const float* __restrict__ ref,           // fp32 NCHW (LOSS only)
               float* __restrict__ acc_out)
{
    constexpr int CC   = (Ci >= 32) ? Ci/32 : 1;
    constexpr int PXB  = Ci*2;                     // bytes per pixel in slab
    constexpr int NCB  = PXB/16;                   // 16B chunks per pixel
    constexpr int SLAB = 6*66*PXB;
    constexpr int NT   = Co/16;
    constexpr int GNT  = (NT >= 2) ? 2 : 1;        // nt-tiles per B-batch
    constexpr int NG   = NT / GNT;
    constexpr int EPIW = 64*(Co+8)*2;              // per-wave epilogue tile
    constexpr int RECB = 64*272*2;                 // LOSS rec tile [64co][4row][68px]
    constexpr int LDSZ = LOSS ? (RECB > SLAB ? RECB : SLAB)
                              : (4*EPIW > SLAB ? 4*EPIW : SLAB);
    __shared__ alignas(16) char slab[LDSZ + 32];
    __shared__ float wred[4];

    const int tid  = threadIdx.x;
    const int lane = tid & 63;
    const int wid  = tid >> 6;
    const int col  = lane & 15;
    const int quad = lane >> 4;
    const int w0   = blockIdx.x * 64;
    const int h0   = blockIdx.y * 4;
    const int bz   = blockIdx.z;
    const int r    = wid;

    floatx4 acc[4][NT];
#pragma unroll
    for (int mt = 0; mt < 4; ++mt)
#pragma unroll
        for (int nt = 0; nt < NT; ++nt)
            acc[mt][nt] = (floatx4)0.f;

    const __hip_bfloat16* inb = in + (size_t)bz * PH * PW * Ci;

    // ---- stage slab: rows h0..h0+5, cols w0..w0+65, all Ci. Coalesced 16B.
    for (int o = tid*16; o < SLAB; o += 4096) {
        int pxl = o / PXB;
        int row = pxl / 66;
        int pxc = pxl - row*66;
        int cb  = (o >> 4) & (NCB-1);
        short8 v = *(const short8*)(inb + ((size_t)(h0+row)*PW + (w0+pxc))*Ci + cb*8);
        *(short8*)(slab + pxl*PXB + ((cb ^ (pxl & (NCB-1))) << 4)) = v;
    }
    __syncthreads();

    if constexpr (Ci >= 32) {
#pragma unroll
        for (int c2 = 0; c2 < CC; ++c2) {
#pragma unroll
            for (int g = 0; g < NG; ++g) {
                short8 bfr[9*GNT];     // batched independent B loads
#pragma unroll
                for (int t = 0; t < 9; ++t)
#pragma unroll
                    for (int j = 0; j < GNT; ++j)
                        bfr[t*GNT+j] = *(const short8*)(wt
                            + ((size_t)(c2*9+t)*Co + (g*GNT+j)*16 + col)*32 + quad*8);
#pragma unroll
                for (int t = 0; t < 9; ++t) {
                    const int dy = t/3, dx = t - (t/3)*3;
                    short8 a[4];
#pragma unroll
                    for (int mt = 0; mt < 4; ++mt) {
                        int px = (r+dy)*66 + mt*16 + col + dx;
                        a[mt] = *(const short8*)(slab + px*PXB
                                  + (((c2*4 + quad) ^ (px & (NCB-1))) << 4));
                    }
#pragma unroll
                    for (int j = 0; j < GNT; ++j)
#pragma unroll
                        for (int mt = 0; mt < 4; ++mt)
                            acc[mt][g*GNT+j] = __builtin_amdgcn_mfma_f32_16x16x32_bf16(
                                a[mt], bfr[t*GNT+j], acc[mt][g*GNT+j], 0, 0, 0);
                }
            }
        }
    } else {
        // Ci=16: K=32 packs 2 dx taps; half1 upper quads carry zero weights.
        short8 bfr[6*NT];
#pragma unroll
        for (int kc = 0; kc < 6; ++kc)
#pragma unroll
            for (int j = 0; j < NT; ++j)
                bfr[kc*NT+j] = *(const short8*)(wt
                    + ((size_t)kc*Co + j*16 + col)*32 + quad*8);
#pragma unroll
        for (int kc = 0; kc < 6; ++kc) {
            const int dy = kc >> 1, half = kc & 1;
            const int dxe = half ? 2 : (quad >> 1);
            short8 a[4];
#pragma unroll
            for (int mt = 0; mt < 4; ++mt) {
                int px = (r+dy)*66 + mt*16 + col + dxe;
                a[mt] = *(const short8*)(slab + px*PXB
                          + (((quad & 1) ^ (px & 1)) << 4));
            }
#pragma unroll
            for (int j = 0; j < NT; ++j)
#pragma unroll
                for (int mt = 0; mt < 4; ++mt)
                    acc[mt][j] = __builtin_amdgcn_mfma_f32_16x16x32_bf16(
                        a[mt], bfr[kc*NT+j], acc[mt][j], 0, 0, 0);
        }
    }

    if constexpr (!LOSS) {
        __syncthreads();
        char* rt = slab + wid * EPIW;     // per-wave [64 px][Co+8] bf16 tile
#pragma unroll
        for (int nt = 0; nt < NT; ++nt) {
            float bv = bias[nt*16 + col];
#pragma unroll
            for (int mt = 0; mt < 4; ++mt) {
#pragma unroll
                for (int rr = 0; rr < 4; ++rr) {
                    float v = acc[mt][nt][rr] + bv;
                    v = v > 0.f ? v : 0.f;
                    int px = mt*16 + quad*4 + rr;
                    *(__hip_bfloat16*)(rt + (px*(Co+8) + nt*16 + col)*2) =
                        __float2bfloat16(v);
                }
            }
        }
        char* grow = (char*)outp
            + (((size_t)bz*PH + (h0 + r + 1))*PW + (w0 + 1))*Co*2;
        constexpr int GB = 64*Co*2;
#pragma unroll
        for (int id = 0; id < GB/1024; ++id) {
            int o  = id*1024 + lane*16;
            int px = o / (Co*2);
            int cb = o - px*(Co*2);
            *(short8*)(grow + o) = *(const short8*)(rt + px*(Co+8)*2 + cb);
        }
    } else {
        // ---- rec -> LDS bf16 [co][row][68] (b64-aligned), barriered
        __syncthreads();                        // all slab reads complete
        __hip_bfloat16* rec = (__hip_bfloat16*)slab;
#pragma unroll
        for (int nt = 0; nt < NT; ++nt) {
            int co = nt*16 + col;
            float bv = bias[co];
#pragma unroll
            for (int mt = 0; mt < 4; ++mt) {
                short4v pk;
#pragma unroll
                for (int rr = 0; rr < 4; ++rr) {
                    float v = acc[mt][nt][rr] + bv;
                    v = v > 0.f ? v : 0.f;
                    pk[rr] = __builtin_bit_cast(short, __float2bfloat16(v));
                }
                *(short4v*)(rec + co*272 + r*68 + mt*16 + quad*4) = pk;
            }
        }
        __syncthreads();

        // ---- coalesced fp32 ref compare: 16 iters, 256B contiguous per co
        float lsum = 0.f;
        const float* refb = ref + (size_t)bz * 64 * H_ * W_;
#pragma unroll
        for (int i = 0; i < 16; ++i) {
            int row = i & 3, cg = i >> 2;
            int co  = cg*16 + wid*4 + quad;
            float4 f = *(const float4*)(refb
                + ((size_t)co*H_ + h0 + row)*W_ + w0 + col*4);
            short4v pk = *(const short4v*)(rec + co*272 + row*68 + col*4);
            float d0 = f.x - __bfloat162float(__builtin_bit_cast(__hip_bfloat16, pk[0]));
            float d1 = f.y - __bfloat162float(__builtin_bit_cast(__hip_bfloat16, pk[1]));
            float d2 = f.z - __bfloat162float(__builtin_bit_cast(__hip_bfloat16, pk[2]));
            float d3 = f.w - __bfloat162float(__builtin_bit_cast(__hip_bfloat16, pk[3]));
            lsum += d0*d0 + d1*d1 + d2*d2 + d3*d3;
        }
#pragma unroll
        for (int off = 32; off > 0; off >>= 1)
            lsum += __shfl_down(lsum, off, 64);
        if (lane == 0) wred[wid] = lsum;
        __syncthreads();
        if (tid == 0)
            atomicAdd(acc_out, wred[0] + wred[1] + wred[2] + wred[3]);
    }
}

// ---------------------------------------------------------------------------
// fp32 NCHW feat -> bf16 padded-NHWC interior. LDS transpose; short4 stores.
// ---------------------------------------------------------------------------
__global__ __launch_bounds__(256)
void feat_to_nhwc(const float* __restrict__ src, __hip_bfloat16* __restrict__ dst)
{
    __shared__ float tile[64][65];
    const int tid = threadIdx.x;
    const int w0 = blockIdx.x * 64;
    const int h  = blockIdx.y;
    const int bz = blockIdx.z;

#pragma unroll
    for (int i = 0; i < 16; ++i) {
        int c = i*4 + (tid >> 6);
        int w = tid & 63;
        tile[c][w] = src[(((size_t)bz*64 + c)*H_ + h)*W_ + w0 + w];
    }
    __syncthreads();
    // write: 4 iters, each thread stores 4 consecutive channels (8 B)
#pragma unroll
    for (int i = 0; i < 4; ++i) {
        int w  = i*16 + (tid >> 4);
        int c4 = (tid & 15) * 4;
        short4v pk;
#pragma unroll
        for (int j = 0; j < 4; ++j)
            pk[j] = __builtin_bit_cast(short, __float2bfloat16(tile[c4 + j][w]));
        *(short4v*)(dst + (((size_t)bz*PH + (h+1))*PW + (w0 + w + 1))*64 + c4) = pk;
    }
}

// ---------------------------------------------------------------------------
// Zero only the pad border cells of a padded NHWC buffer (772 px / image).
// ---------------------------------------------------------------------------
template<int C>
__global__ void zero_border(__hip_bfloat16* buf)
{
    constexpr int CP = C/8;
    int idx = blockIdx.x*256 + threadIdx.x;
    int total = B_ * 772 * CP;
    if (idx >= total) return;
    int cb   = idx % CP;
    int cell = (idx / CP) % 772;
    int img  = idx / (CP*772);
    int row, colp;
    if (cell < 258)      { row = 0;   colp = cell; }
    else if (cell < 516) { row = 129; colp = cell - 258; }
    else { int r2 = cell - 516; row = 1 + (r2 >> 1); colp = (r2 & 1) ? 257 : 0; }
    short8 z = (short8)0;
    *(short8*)(buf + (((size_t)img*PH + row)*PW + colp)*C + cb*8) = z;
}

// ---------------------------------------------------------------------------
// OIHW fp32 -> [KC][Co][32] bf16 B-operand layout. Ci>=32: kc = c2*9 + tap.
// Ci=16: kc = dy*2+half; dx slot 3 = zero.
// ---------------------------------------------------------------------------
template<int Ci, int Co>
__global__ void wt_transform(const float* __restrict__ w, __hip_bfloat16* __restrict__ wt)
{
    constexpr int KC = (Ci >= 32) ? 9*(Ci/32) : 6;
    int idx = blockIdx.x*256 + threadIdx.x;
    if (idx >= KC*Co*32) return;
    int kl = idx & 31;
    int co = (idx >> 5) % Co;
    int kc = idx / (32*Co);
    float val = 0.f;
    if (Ci >= 32) {
        int c2 = kc / 9, t = kc % 9;
        int dy = t/3, dx = t%3;
        int ci = c2*32 + kl;
        val = w[((size_t)(co*Ci + ci)*3 + dy)*3 + dx];
    } else {
        int dy = kc >> 1, half = kc & 1;
        int dx = half*2 + (kl >> 4);
        int ci = kl & 15;
        if (dx < 3) val = w[((size_t)(co*Ci + ci)*3 + dy)*3 + dx];
    }
    wt[idx] = __float2bfloat16(val);
}

// fused_feat = 0.5*(feat0+feat1) exactly (the m-softmax collapses to 1/2).
__global__ __launch_bounds__(256)
void fused_avg_kernel(const float4* __restrict__ a, const float4* __restrict__ b,
                      float4* __restrict__ o, int n4)
{
    int i = blockIdx.x*256 + threadIdx.x;
    if (i < n4) {
        float4 x = a[i], y = b[i];
        float4 r;
        r.x = 0.5f*(x.x + y.x);
        r.y = 0.5f*(x.y + y.y);
        r.z = 0.5f*(x.z + y.z);
        r.w = 0.5f*(x.w + y.w);
        o[i] = r;
    }
}

__global__ void finalize_loss_kernel(float* acc)
{
    *acc *= (1.0f / (float)NPIX);
}

extern "C" void kernel_launch(void* const* d_in, const int* in_sizes, int n_in,
                              void* d_out, int out_size, void* d_ws, size_t ws_size,
                              hipStream_t stream)
{
    const float* feat0 = (const float*)d_in[0];
    const float* feat1 = (const float*)d_in[1];
    const float* w1 = (const float*)d_in[2];
    const float* b1 = (const float*)d_in[3];
    const float* w2 = (const float*)d_in[4];
    const float* b2 = (const float*)d_in[5];
    const float* w3 = (const float*)d_in[6];
    const float* b3 = (const float*)d_in[7];
    const float* w4 = (const float*)d_in[8];
    const float* b4 = (const float*)d_in[9];

    float* out = (float*)d_out;
    char*  base = (char*)d_out;

    __hip_bfloat16* TF   = (__hip_bfloat16*)(base + 0);           // 64ch padded NHWC
    __hip_bfloat16* BUF1 = (__hip_bfloat16*)(base + 34344960);    // 32ch
    __hip_bfloat16* BUF2 = (__hip_bfloat16*)(base + 51517440);    // 16ch
    __hip_bfloat16* WT1  = (__hip_bfloat16*)(base + 60103680);    // 18*32*32
    __hip_bfloat16* WT2  = (__hip_bfloat16*)(base + 60140544);    //  9*16*32
    __hip_bfloat16* WT3  = (__hip_bfloat16*)(base + 60149760);    //  6*32*32
    __hip_bfloat16* WT4  = (__hip_bfloat16*)(base + 60162048);    //  9*64*32
    float* acc = out + NPIX;                                      // loss slot

    hipMemsetAsync(acc, 0, sizeof(float), stream);

    zero_border<64><<<(B_*772*8  + 255)/256, 256, 0, stream>>>(TF);
    zero_border<32><<<(B_*772*4  + 255)/256, 256, 0, stream>>>(BUF1);
    zero_border<16><<<(B_*772*2  + 255)/256, 256, 0, stream>>>(BUF2);

    wt_transform<64,32><<<(18*32*32 + 255)/256, 256, 0, stream>>>(w1, WT1);
    wt_transform<32,16><<<( 9*16*32 + 255)/256, 256, 0, stream>>>(w2, WT2);
    wt_transform<16,32><<<( 6*32*32 + 255)/256, 256, 0, stream>>>(w3, WT3);
    wt_transform<32,64><<<( 9*64*32 + 255)/256, 256, 0, stream>>>(w4, WT4);

    dim3 cgrid(W_/64, H_/4, B_);      // 1024 blocks
    dim3 blk(256);
    dim3 tgrid(W_/64, H_, B_);

    const float* feats[2] = { feat0, feat1 };
    for (int m = 0; m < 2; ++m) {
        feat_to_nhwc<<<tgrid, blk, 0, stream>>>(feats[m], TF);
        conv_mfma<64,32,false><<<cgrid, blk, 0, stream>>>(TF,   WT1, b1, BUF1, nullptr, nullptr);
        conv_mfma<32,16,false><<<cgrid, blk, 0, stream>>>(BUF1, WT2, b2, BUF2, nullptr, nullptr);
        conv_mfma<16,32,false><<<cgrid, blk, 0, stream>>>(BUF2, WT3, b3, BUF1, nullptr, nullptr);
        conv_mfma<32,64,true ><<<cgrid, blk, 0, stream>>>(BUF1, WT4, b4, nullptr, feats[m], acc);
    }

    int n4 = NPIX/4;
    fused_avg_kernel<<<(n4 + 255)/256, 256, 0, stream>>>(
        (const float4*)feat0, (const float4*)feat1, (float4*)out, n4);

    finalize_loss_kernel<<<1, 1, 0, stream>>>(acc);
}